// Round 3
// baseline (629.034 us; speedup 1.0000x reference)
//
#include <hip/hip_runtime.h>
#include <hip/hip_bf16.h>
#include <hip/hip_fp16.h>

#define T_TOK 8192
#define HDIM  1024
#define FDIM  4096
#define NEXP  8
#define CAP   1024

typedef _Float16 f16x8 __attribute__((ext_vector_type(8)));
typedef float    f32x4 __attribute__((ext_vector_type(4)));

__device__ __forceinline__ unsigned short f2h_u(float f) {
    _Float16 h = (_Float16)f;
    return __builtin_bit_cast(unsigned short, h);
}

#define GLOAD_LDS16(gp, lp)                                                              \
    __builtin_amdgcn_global_load_lds((const __attribute__((address_space(1))) void*)(gp),\
                                     (__attribute__((address_space(3))) void*)(lp),      \
                                     16, 0, 0)

// ---------------- gating: logits = x @ Wg, softmax, argmax ----------------
__global__ __launch_bounds__(256) void gate_kernel(const float* __restrict__ x,
                                                   const float* __restrict__ Wg,
                                                   int* __restrict__ eidx,
                                                   float* __restrict__ gate) {
    __shared__ float wgt[NEXP * HDIM];   // transposed [e][h], conflict-free reads
    const int tid = threadIdx.x;
    for (int i = tid; i < NEXP * HDIM; i += 256) {
        int h = i >> 3, e = i & 7;
        wgt[e * HDIM + h] = Wg[i];
    }
    __syncthreads();
    const int lane = tid & 63;
    const int t = blockIdx.x * 4 + (tid >> 6);
    const float* xr = x + (size_t)t * HDIM;
    float acc[NEXP];
#pragma unroll
    for (int e = 0; e < NEXP; e++) acc[e] = 0.f;
    for (int h = lane; h < HDIM; h += 64) {
        float xv = xr[h];
#pragma unroll
        for (int e = 0; e < NEXP; e++) acc[e] += xv * wgt[e * HDIM + h];
    }
#pragma unroll
    for (int e = 0; e < NEXP; e++) {
#pragma unroll
        for (int s = 32; s > 0; s >>= 1) acc[e] += __shfl_xor(acc[e], s);
    }
    if (lane == 0) {
        float mx = acc[0]; int mi = 0;
#pragma unroll
        for (int e = 1; e < NEXP; e++) { if (acc[e] > mx) { mx = acc[e]; mi = e; } }
        float den = 0.f;
#pragma unroll
        for (int e = 0; e < NEXP; e++) den += expf(acc[e] - mx);
        eidx[t] = mi;
        gate[t] = 1.0f / den;    // softmax value at the argmax
    }
}

// ---------------- capacity scan: one wave per expert ----------------
__global__ __launch_bounds__(512) void scan_kernel(const int* __restrict__ eidx,
                                                   const float* __restrict__ gate,
                                                   int* __restrict__ tok,
                                                   float* __restrict__ gslot) {
    __shared__ int sidx[T_TOK];
    for (int i = threadIdx.x; i < T_TOK; i += 512) sidx[i] = eidx[i];
    __syncthreads();
    const int e = threadIdx.x >> 6, lane = threadIdx.x & 63;
    const unsigned long long below = (lane == 0) ? 0ull : (~0ull >> (64 - lane));
    int cnt = 0;
    for (int c0 = 0; c0 < T_TOK; c0 += 64) {
        int t = c0 + lane;
        int my = sidx[t];
        unsigned long long b = __ballot(my == e);
        if (my == e) {
            int pos = cnt + __popcll(b & below);
            if (pos < CAP) { tok[e * CAP + pos] = t; gslot[e * CAP + pos] = gate[t]; }
        }
        cnt += __popcll(b);
    }
}

// ---------------- gather tokens -> A f16 [E][C][H] ----------------
__global__ __launch_bounds__(256) void gather_kernel(const float* __restrict__ x,
                                                     const int* __restrict__ tok,
                                                     unsigned short* __restrict__ A) {
    const int row = blockIdx.x;          // e*CAP + c
    const int t = tok[row];
    unsigned short* dst = A + (size_t)row * HDIM;
    if (t < 0) {
        ushort4 z; z.x = z.y = z.z = z.w = 0;
        ((ushort4*)dst)[threadIdx.x] = z;
    } else {
        float4 v = ((const float4*)(x + (size_t)t * HDIM))[threadIdx.x];
        ushort4 o;
        o.x = f2h_u(v.x); o.y = f2h_u(v.y); o.z = f2h_u(v.z); o.w = f2h_u(v.w);
        ((ushort4*)dst)[threadIdx.x] = o;
    }
}

// ---------------- transpose+convert: f32 [E][R][Cdim] -> f16 [E][Cdim][R] ----------------
__global__ __launch_bounds__(256) void transpose_kernel(const float* __restrict__ in,
                                                        unsigned short* __restrict__ out,
                                                        int R, int Cdim) {
    __shared__ unsigned short tile[64][72];
    const int e = blockIdx.z;
    const size_t esz = (size_t)R * Cdim;
    const float* ine = in + e * esz;
    unsigned short* oute = out + e * esz;
    const int r0 = blockIdx.y * 64, c0 = blockIdx.x * 64;
    const int tid = threadIdx.x;
    const int rr = tid >> 4;
    const int c4 = (tid & 15) * 4;
#pragma unroll
    for (int rb = 0; rb < 64; rb += 16) {
        int r = rb + rr;
        float4 v = *(const float4*)&ine[(size_t)(r0 + r) * Cdim + c0 + c4];
        tile[c4 + 0][r] = f2h_u(v.x);
        tile[c4 + 1][r] = f2h_u(v.y);
        tile[c4 + 2][r] = f2h_u(v.z);
        tile[c4 + 3][r] = f2h_u(v.w);
    }
    __syncthreads();
    const int c = tid >> 2;
    const int rseg = (tid & 3) * 16;
    ushort4 o0 = *(const ushort4*)&tile[c][rseg + 0];
    ushort4 o1 = *(const ushort4*)&tile[c][rseg + 4];
    ushort4 o2 = *(const ushort4*)&tile[c][rseg + 8];
    ushort4 o3 = *(const ushort4*)&tile[c][rseg + 12];
    unsigned short* op = &oute[(size_t)(c0 + c) * R + r0 + rseg];
    ((ushort4*)op)[0] = o0; ((ushort4*)op)[1] = o1;
    ((ushort4*)op)[2] = o2; ((ushort4*)op)[3] = o3;
}

// ---------------- GEMM1: hidden = relu(A @ W1 + b1), f16 out ----------------
// A [E][CAP][HDIM] f16, Bt = W1t [E][FDIM][HDIM] f16 (K-contiguous rows)
__global__ __launch_bounds__(256) void gemm1_kernel(const unsigned short* __restrict__ A,
                                                    const unsigned short* __restrict__ Bt,
                                                    const float* __restrict__ b1,
                                                    unsigned short* __restrict__ hid) {
    __shared__ __align__(16) unsigned short As[128 * 64];
    __shared__ __align__(16) unsigned short Bs[128 * 64];
    const int e = blockIdx.z;
    const int m0 = blockIdx.y * 128;
    const int n0 = blockIdx.x * 128;
    const int tid = threadIdx.x;
    const int lane = tid & 63;
    const int wr = ((tid >> 7) & 1) * 64;
    const int wc = ((tid >> 6) & 1) * 64;
    const unsigned short* Ae = A + ((size_t)e * CAP + m0) * HDIM;
    const unsigned short* Be = Bt + ((size_t)e * FDIM + n0) * HDIM;
    f32x4 acc[4][4];
    f32x4 zz = {0.f, 0.f, 0.f, 0.f};
#pragma unroll
    for (int i = 0; i < 4; i++)
#pragma unroll
        for (int j = 0; j < 4; j++) acc[i][j] = zz;

    const int srow = tid >> 3;     // 0..31
    const int sslot = tid & 7;
    for (int k0 = 0; k0 < HDIM; k0 += 64) {
#pragma unroll
        for (int j = 0; j < 4; j++) {
            int row = j * 32 + srow;
            int col = k0 + ((sslot ^ (row & 7)) << 3);   // XOR-swizzled source
            GLOAD_LDS16(Ae + (size_t)row * HDIM + col, &As[(size_t)(j * 256 + tid) * 8]);
            GLOAD_LDS16(Be + (size_t)row * HDIM + col, &Bs[(size_t)(j * 256 + tid) * 8]);
        }
        __syncthreads();
#pragma unroll
        for (int ks = 0; ks < 2; ks++) {
            f16x8 af[4], bfr[4];
#pragma unroll
            for (int mi = 0; mi < 4; mi++) {
                int row = wr + mi * 16 + (lane & 15);
                int slotk = ks * 4 + (lane >> 4);
                af[mi] = *(const f16x8*)((const char*)As + row * 128 + ((slotk ^ (row & 7)) << 4));
            }
#pragma unroll
            for (int ni = 0; ni < 4; ni++) {
                int row = wc + ni * 16 + (lane & 15);
                int slotk = ks * 4 + (lane >> 4);
                bfr[ni] = *(const f16x8*)((const char*)Bs + row * 128 + ((slotk ^ (row & 7)) << 4));
            }
#pragma unroll
            for (int mi = 0; mi < 4; mi++)
#pragma unroll
                for (int ni = 0; ni < 4; ni++)
                    acc[mi][ni] = __builtin_amdgcn_mfma_f32_16x16x32_f16(af[mi], bfr[ni], acc[mi][ni], 0, 0, 0);
        }
        __syncthreads();
    }
    const int r4 = (lane >> 4) * 4;
#pragma unroll
    for (int ni = 0; ni < 4; ni++) {
        int col = n0 + wc + ni * 16 + (lane & 15);
        float bv = b1[e * FDIM + col];
#pragma unroll
        for (int mi = 0; mi < 4; mi++) {
#pragma unroll
            for (int j = 0; j < 4; j++) {
                int row = m0 + wr + mi * 16 + r4 + j;
                float v = acc[mi][ni][j] + bv;
                hid[((size_t)e * CAP + row) * FDIM + col] = f2h_u(v > 0.f ? v : 0.f);
            }
        }
    }
}

// ---------------- GEMM2: out[tok] = gate * (hidden @ W2 + b2), f32 scatter ----------------
// A = hidden [E][CAP][FDIM] f16, Bt = W2t [E][HDIM][FDIM] f16
__global__ __launch_bounds__(256) void gemm2_kernel(const unsigned short* __restrict__ A,
                                                    const unsigned short* __restrict__ Bt,
                                                    const float* __restrict__ b2,
                                                    const int* __restrict__ tok,
                                                    const float* __restrict__ gslot,
                                                    float* __restrict__ out) {
    __shared__ __align__(16) unsigned short As[128 * 64];
    __shared__ __align__(16) unsigned short Bs[128 * 64];
    __shared__ int ts[128];
    __shared__ float sg[128];
    const int e = blockIdx.z;
    const int m0 = blockIdx.y * 128;
    const int n0 = blockIdx.x * 128;
    const int tid = threadIdx.x;
    if (tid < 128) {
        int t = tok[e * CAP + m0 + tid];
        ts[tid] = t;
        sg[tid] = (t >= 0) ? gslot[e * CAP + m0 + tid] : 0.f;
    }
    const int lane = tid & 63;
    const int wr = ((tid >> 7) & 1) * 64;
    const int wc = ((tid >> 6) & 1) * 64;
    const unsigned short* Ae = A + ((size_t)e * CAP + m0) * FDIM;
    const unsigned short* Be = Bt + ((size_t)e * HDIM + n0) * FDIM;
    f32x4 acc[4][4];
    f32x4 zz = {0.f, 0.f, 0.f, 0.f};
#pragma unroll
    for (int i = 0; i < 4; i++)
#pragma unroll
        for (int j = 0; j < 4; j++) acc[i][j] = zz;

    const int srow = tid >> 3;
    const int sslot = tid & 7;
    for (int k0 = 0; k0 < FDIM; k0 += 64) {
#pragma unroll
        for (int j = 0; j < 4; j++) {
            int row = j * 32 + srow;
            int col = k0 + ((sslot ^ (row & 7)) << 3);
            GLOAD_LDS16(Ae + (size_t)row * FDIM + col, &As[(size_t)(j * 256 + tid) * 8]);
            GLOAD_LDS16(Be + (size_t)row * FDIM + col, &Bs[(size_t)(j * 256 + tid) * 8]);
        }
        __syncthreads();
#pragma unroll
        for (int ks = 0; ks < 2; ks++) {
            f16x8 af[4], bfr[4];
#pragma unroll
            for (int mi = 0; mi < 4; mi++) {
                int row = wr + mi * 16 + (lane & 15);
                int slotk = ks * 4 + (lane >> 4);
                af[mi] = *(const f16x8*)((const char*)As + row * 128 + ((slotk ^ (row & 7)) << 4));
            }
#pragma unroll
            for (int ni = 0; ni < 4; ni++) {
                int row = wc + ni * 16 + (lane & 15);
                int slotk = ks * 4 + (lane >> 4);
                bfr[ni] = *(const f16x8*)((const char*)Bs + row * 128 + ((slotk ^ (row & 7)) << 4));
            }
#pragma unroll
            for (int mi = 0; mi < 4; mi++)
#pragma unroll
                for (int ni = 0; ni < 4; ni++)
                    acc[mi][ni] = __builtin_amdgcn_mfma_f32_16x16x32_f16(af[mi], bfr[ni], acc[mi][ni], 0, 0, 0);
        }
        __syncthreads();
    }
    const int r4 = (lane >> 4) * 4;
#pragma unroll
    for (int ni = 0; ni < 4; ni++) {
        int col = n0 + wc + ni * 16 + (lane & 15);
        float bv = b2[e * HDIM + col];
#pragma unroll
        for (int mi = 0; mi < 4; mi++) {
#pragma unroll
            for (int j = 0; j < 4; j++) {
                int rl = wr + mi * 16 + r4 + j;     // local row in block
                int t = ts[rl];
                if (t >= 0)
                    out[(size_t)t * HDIM + col] = sg[rl] * (acc[mi][ni][j] + bv);
            }
        }
    }
}

extern "C" void kernel_launch(void* const* d_in, const int* in_sizes, int n_in,
                              void* d_out, int out_size, void* d_ws, size_t ws_size,
                              hipStream_t stream) {
    const float* x  = (const float*)d_in[0];
    const float* Wg = (const float*)d_in[1];
    const float* W1 = (const float*)d_in[2];
    const float* b1 = (const float*)d_in[3];
    const float* W2 = (const float*)d_in[4];
    const float* b2 = (const float*)d_in[5];
    float* out = (float*)d_out;

    char* ws = (char*)d_ws;
    const size_t SMALL   = 128 * 1024;
    const size_t A_BYTES = (size_t)T_TOK * HDIM * 2;   // 16.78 MB
    const size_t H_BYTES = (size_t)T_TOK * FDIM * 2;   // 67.1 MB
    const size_t W_BYTES = (size_t)NEXP * HDIM * FDIM * 2; // 67.1 MB

    int*   eidx = (int*)(ws);
    float* gate = (float*)(ws + 32 * 1024);
    int*   tok  = (int*)(ws + 64 * 1024);
    float* gsl  = (float*)(ws + 96 * 1024);
    unsigned short* Abuf = (unsigned short*)(ws + SMALL);
    unsigned short* Hbuf = (unsigned short*)(ws + SMALL + A_BYTES);
    unsigned short* Wt1  = (unsigned short*)(ws + SMALL + A_BYTES + H_BYTES);
    const int two_buf = (ws_size >= SMALL + A_BYTES + H_BYTES + 2 * W_BYTES);
    unsigned short* Wt2 = two_buf ? (Wt1 + W_BYTES / 2) : Wt1;

    hipMemsetAsync(d_out, 0, (size_t)T_TOK * HDIM * 4, stream);
    hipMemsetAsync(tok, 0xFF, NEXP * CAP * 4, stream);

    transpose_kernel<<<dim3(FDIM / 64, HDIM / 64, NEXP), 256, 0, stream>>>(W1, Wt1, HDIM, FDIM);
    if (two_buf)
        transpose_kernel<<<dim3(HDIM / 64, FDIM / 64, NEXP), 256, 0, stream>>>(W2, Wt2, FDIM, HDIM);

    gate_kernel<<<T_TOK / 4, 256, 0, stream>>>(x, Wg, eidx, gate);
    scan_kernel<<<1, 512, 0, stream>>>(eidx, gate, tok, gsl);
    gather_kernel<<<NEXP * CAP, 256, 0, stream>>>(x, tok, Abuf);

    gemm1_kernel<<<dim3(FDIM / 128, CAP / 128, NEXP), 256, 0, stream>>>(Abuf, Wt1, b1, Hbuf);

    if (!two_buf)
        transpose_kernel<<<dim3(HDIM / 64, FDIM / 64, NEXP), 256, 0, stream>>>(W2, Wt2, FDIM, HDIM);

    gemm2_kernel<<<dim3(HDIM / 128, CAP / 128, NEXP), 256, 0, stream>>>(Hbuf, Wt2, b2, tok, gsl, out);
}